// Round 15
// baseline (390.161 us; speedup 1.0000x reference)
//
#include <hip/hip_runtime.h>

#define N_NODES 100000
#define ROWS_PAD 100096
#define NIN 512
#define H1  512
#define H2  128
#define N_EDGES 3200000

typedef __attribute__((ext_vector_type(8))) short bf16x8;
typedef __attribute__((ext_vector_type(4))) float f32x4;
typedef __attribute__((ext_vector_type(2))) float f32x2;

__device__ __forceinline__ unsigned short f2b(float x) {
  union { float f; unsigned int u; } c; c.f = x;
  unsigned int u = c.u;
  unsigned int r = (u + 0x7FFFu + ((u >> 16) & 1u)) >> 16;
  return (unsigned short)r;
}

typedef const __attribute__((address_space(1))) unsigned int* gp1_t;
typedef __attribute__((address_space(3))) unsigned int* sp3_t;
__device__ __forceinline__ void gl_lds16(const void* g, void* s) {
  __builtin_amdgcn_global_load_lds((gp1_t)g, (sp3_t)s, 16, 0, 0);
}

// packed f32x2 -> bf16x2 (RNE), 1 VALU inst
__device__ __forceinline__ unsigned cvtpk(float lo, float hi) {
  unsigned r;
  asm("v_cvt_pk_bf16_f32 %0, %1, %2" : "=v"(r) : "v"(lo), "v"(hi));
  return r;
}

// ---- prep: W1/W2 transpose+bf16 pre-swizzled + CSR row_ptr (one dispatch) ----
__global__ void prep_kernel(const float* __restrict__ W1, const float* __restrict__ W2,
                            const int* __restrict__ rows,
                            unsigned short* __restrict__ W1t, unsigned short* __restrict__ W2t,
                            int* __restrict__ row_ptr) {
  int idx = blockIdx.x * blockDim.x + threadIdx.x;
  int stride = gridDim.x * blockDim.x;
  for (int i = idx; i < H1 * NIN; i += stride) {
    int n = i >> 9, k = i & 511;
    W1t[i] = f2b(W1[(size_t)(k ^ ((n & 7) << 3)) * H1 + n]);
  }
  for (int i = idx; i < H2 * H1; i += stride) {
    int n = i >> 9, k = i & 511;
    W2t[i] = f2b(W2[(size_t)(k ^ ((n & 7) << 3)) * H2 + n]);
  }
  for (int e = idx; e < N_EDGES; e += stride) {
    int r = rows[e];
    int rp = (e == 0) ? -1 : rows[e - 1];
    for (int q = rp + 1; q <= r; ++q) row_ptr[q] = e;
  }
  int lastrow = rows[N_EDGES - 1];
  for (int q = idx; q <= N_NODES; q += stride)
    if (q > lastrow) row_ptr[q] = N_EDGES;
}

// ---- fused MLP: ha = relu(seq_a@W1+b1)@W2+b2 -> f32 d_out + fp8 table ----
// LDS bytes: A bf16 [0,8192) | B (W1 chunk) [8192,24576) | T bf16 [24576,40960)
__global__ __launch_bounds__(256, 4) void mlp_kernel(
    const float* __restrict__ A, const unsigned short* __restrict__ W1t,
    const unsigned short* __restrict__ W2t, const float* __restrict__ b1,
    const float* __restrict__ b2, float* __restrict__ ha_out, unsigned char* __restrict__ ha8)
{
  __shared__ __align__(16) unsigned short SM[20480];   // 40 KB
  const int tid = threadIdx.x;
  const int w = tid >> 6, lane = tid & 63;
  const int l15 = lane & 15, lg = lane >> 4;
  const int wr = w & 1, wc = w >> 1;
  const int row0 = blockIdx.x << 6;

  // A staging: 4 threads/row, 16 f32 (64B) per thread per kt
  int arow = row0 + (tid >> 2);
  if (arow > N_NODES - 1) arow = N_NODES - 1;           // OOB clamp (stores masked later)
  const float* asrc = A + ((size_t)arow << 9) + ((tid & 3) << 4);
  const int alr  = tid >> 2;
  const int aswz = (alr & 7) << 4;
  const int ad0  = ((tid & 3) << 5);
  char* alds = (char*)SM + alr * 128;

  const int so = tid * 16;

  f32x4 acc_ha[2][4];
  #pragma unroll
  for (int m = 0; m < 2; ++m)
    #pragma unroll
    for (int n = 0; n < 4; ++n) acc_ha[m][n] = (f32x4){0.f, 0.f, 0.f, 0.f};

  #pragma unroll 1
  for (int nc = 0; nc < 4; ++nc) {
    // per-nc prologue: A(0) regs (B(0) is issued inside kt=0, before these are consumed)
    f32x4 a0 = *(const f32x4*)(asrc);
    f32x4 a1 = *(const f32x4*)(asrc + 4);
    f32x4 a2 = *(const f32x4*)(asrc + 8);
    f32x4 a3 = *(const f32x4*)(asrc + 12);

    f32x4 accT[2][4];
    #pragma unroll
    for (int m = 0; m < 2; ++m)
      #pragma unroll
      for (int n = 0; n < 4; ++n) accT[m][n] = (f32x4){0.f, 0.f, 0.f, 0.f};

    #pragma unroll
    for (int kt = 0; kt < 8; ++kt) {
      // B(kt): W1t rows nc*128..+127, k-slice kt -> LDS (4 ops; drained by vmcnt(4) below)
      #pragma unroll
      for (int it = 0; it < 4; ++it) {
        int o = it * 4096 + so;
        int r = o >> 7, kb = o & 127;
        gl_lds16((const char*)W1t + (((size_t)((nc << 7) + r)) << 10) + (kt << 7) + kb,
                 (char*)SM + 8192 + o);
      }
      // convert A(kt) + ds_write (compiler waits A(kt) loads — oldest outstanding)
      uint4 w0, w1;
      w0.x = cvtpk(a0[0], a0[1]); w0.y = cvtpk(a0[2], a0[3]);
      w0.z = cvtpk(a1[0], a1[1]); w0.w = cvtpk(a1[2], a1[3]);
      w1.x = cvtpk(a2[0], a2[1]); w1.y = cvtpk(a2[2], a2[3]);
      w1.z = cvtpk(a3[0], a3[1]); w1.w = cvtpk(a3[2], a3[3]);
      *(uint4*)(alds + ((ad0 +  0) ^ aswz)) = w0;
      *(uint4*)(alds + ((ad0 + 16) ^ aswz)) = w1;
      __builtin_amdgcn_sched_barrier(0);
      // prefetch A(kt+1) regs (newest vmem; in flight across MFMA)
      if (kt < 7) {
        const float* anp = asrc + ((kt + 1) << 6);
        a0 = *(const f32x4*)(anp);
        a1 = *(const f32x4*)(anp + 4);
        a2 = *(const f32x4*)(anp + 8);
        a3 = *(const f32x4*)(anp + 12);
        __builtin_amdgcn_sched_barrier(0);
        asm volatile("s_waitcnt vmcnt(4) lgkmcnt(0)" ::: "memory");  // drain B(kt)+ds; keep A(kt+1)
      } else {
        __builtin_amdgcn_sched_barrier(0);
        asm volatile("s_waitcnt vmcnt(0) lgkmcnt(0)" ::: "memory");
      }
      __builtin_amdgcn_s_barrier();
      __builtin_amdgcn_sched_barrier(0);
      #pragma unroll
      for (int ks = 0; ks < 2; ++ks) {
        bf16x8 af[2], bfr[4];
        #pragma unroll
        for (int m = 0; m < 2; ++m) {
          int r = wr * 32 + m * 16 + l15;
          af[m] = *(const bf16x8*)((const char*)SM + (r << 7) + (((ks << 6) + (lg << 4)) ^ ((r & 7) << 4)));
        }
        #pragma unroll
        for (int n = 0; n < 4; ++n) {
          int r = wc * 64 + n * 16 + l15;
          bfr[n] = *(const bf16x8*)((const char*)SM + 8192 + (r << 7) + (((ks << 6) + (lg << 4)) ^ ((r & 7) << 4)));
        }
        #pragma unroll
        for (int m = 0; m < 2; ++m)
          #pragma unroll
          for (int n = 0; n < 4; ++n)
            accT[m][n] = __builtin_amdgcn_mfma_f32_16x16x32_bf16(af[m], bfr[n], accT[m][n], 0, 0, 0);
      }
      __builtin_amdgcn_sched_barrier(0);
      __builtin_amdgcn_s_barrier();   // all waves' ds_reads retired before next kt's writes
    }

    // ---- T = bias+relu(accT) -> LDS bf16 (swizzled, 256B rows) ----
    #pragma unroll
    for (int n = 0; n < 4; ++n) {
      int cl = wc * 64 + n * 16 + l15;
      float bias = b1[(nc << 7) + cl];
      #pragma unroll
      for (int m = 0; m < 2; ++m) {
        #pragma unroll
        for (int q = 0; q < 4; ++q) {
          int rl = wr * 32 + m * 16 + lg * 4 + q;
          float v = accT[m][n][q] + bias;
          v = v > 0.f ? v : 0.f;
          *(unsigned short*)((char*)SM + 24576 + rl * 256 + (((cl << 1)) ^ ((rl & 7) << 4))) = f2b(v);
        }
      }
    }
    __syncthreads();

    // ---- GEMM2 partial: acc_ha += T @ W2t[:, nc-slice]; B-frags direct from L2 ----
    #pragma unroll
    for (int kk = 0; kk < 4; ++kk) {
      bf16x8 bw[4];
      #pragma unroll
      for (int nf = 0; nf < 4; ++nf) {
        int n = wc * 64 + nf * 16 + l15;
        int kl = (nc << 7) + (kk << 5) + (lg << 3);
        bw[nf] = *(const bf16x8*)(W2t + ((size_t)n << 9) + (kl ^ ((n & 7) << 3)));
      }
      bf16x8 af[2];
      #pragma unroll
      for (int m = 0; m < 2; ++m) {
        int r = wr * 32 + m * 16 + l15;
        af[m] = *(const bf16x8*)((const char*)SM + 24576 + (r << 8) + (((kk << 6) + (lg << 4)) ^ ((r & 7) << 4)));
      }
      #pragma unroll
      for (int m = 0; m < 2; ++m)
        #pragma unroll
        for (int nf = 0; nf < 4; ++nf)
          acc_ha[m][nf] = __builtin_amdgcn_mfma_f32_16x16x32_bf16(af[m], bw[nf], acc_ha[m][nf], 0, 0, 0);
    }
    __syncthreads();   // T reads done before next nc's kt-loop re-syncs (and A/B rewrites)
  }

  // ---- epilogue: + b2 -> f32 ha_out + fp8 table ----
  #pragma unroll
  for (int nf = 0; nf < 4; ++nf) {
    int col = wc * 64 + nf * 16 + l15;
    float bias = b2[col];
    #pragma unroll
    for (int m = 0; m < 2; ++m) {
      #pragma unroll
      for (int q = 0; q < 4; ++q) {
        int row = row0 + wr * 32 + m * 16 + lg * 4 + q;
        if (row < N_NODES) {
          float v = acc_ha[m][nf][q] + bias;
          ha_out[((size_t)row << 7) + col] = v;
          int p8 = __builtin_amdgcn_cvt_pk_fp8_f32(v, v, 0, false);
          ha8[((size_t)row << 7) + col] = (unsigned char)(p8 & 0xff);
        }
      }
    }
  }
}

// ---- aggregation: CSR, one wave per row, fp8 table (2 cache lines/edge), no atomics ----
__global__ __launch_bounds__(256) void agg_csr_kernel(
    const int* __restrict__ row_ptr, const int* __restrict__ cols, const float* __restrict__ vals,
    const unsigned char* __restrict__ gtab8, float* __restrict__ hp)
{
  const int row = __builtin_amdgcn_readfirstlane((blockIdx.x * blockDim.x + threadIdx.x) >> 6);
  if (row >= N_NODES) return;
  const int lane = threadIdx.x & 63;
  const int e0 = row_ptr[row];
  const int e1 = row_ptr[row + 1];

  float acc0 = 0.f, acc1 = 0.f;
  int e = e0;
  for (; e + 8 <= e1; e += 8) {
    int c[8]; float v[8]; unsigned short g[8];
    #pragma unroll
    for (int j = 0; j < 8; ++j) { c[j] = cols[e + j]; v[j] = vals[e + j]; }
    #pragma unroll
    for (int j = 0; j < 8; ++j)
      g[j] = *(const unsigned short*)(gtab8 + ((size_t)c[j] << 7) + (lane << 1));
    float t0 = acc0, t1 = 0.f, u0 = acc1, u1 = 0.f;
    #pragma unroll
    for (int j = 0; j < 8; j += 2) {
      f32x2 f0 = __builtin_amdgcn_cvt_pk_f32_fp8((int)g[j+0], false);
      f32x2 f1 = __builtin_amdgcn_cvt_pk_f32_fp8((int)g[j+1], false);
      t0 = fmaf(v[j+0], f0.x, t0);
      t1 = fmaf(v[j+1], f1.x, t1);
      u0 = fmaf(v[j+0], f0.y, u0);
      u1 = fmaf(v[j+1], f1.y, u1);
    }
    acc0 = t0 + t1; acc1 = u0 + u1;
  }
  for (; e < e1; ++e) {
    int c = cols[e];
    float v = vals[e];
    unsigned short g = *(const unsigned short*)(gtab8 + ((size_t)c << 7) + (lane << 1));
    f32x2 f = __builtin_amdgcn_cvt_pk_f32_fp8((int)g, false);
    acc0 = fmaf(v, f.x, acc0);
    acc1 = fmaf(v, f.y, acc1);
  }
  float2 st; st.x = acc0; st.y = acc1;
  *(float2*)&hp[((size_t)row << 7) + (lane << 1)] = st;
}

extern "C" void kernel_launch(void* const* d_in, const int* in_sizes, int n_in,
                              void* d_out, int out_size, void* d_ws, size_t ws_size,
                              hipStream_t stream) {
  const float* seq_a    = (const float*)d_in[0];
  const float* W1       = (const float*)d_in[1];
  const float* b1       = (const float*)d_in[2];
  const float* W2       = (const float*)d_in[3];
  const float* b2       = (const float*)d_in[4];
  const int*   adj_rows = (const int*)d_in[5];
  const int*   adj_cols = (const int*)d_in[6];
  const float* adj_vals = (const float*)d_in[7];

  unsigned short* W1t   = (unsigned short*)d_ws;            // 512 x 512 bf16 (pre-swizzled)
  unsigned short* W2t   = W1t + (size_t)H1 * NIN;           // 128 x 512 bf16 (pre-swizzled)
  unsigned char*  ha8   = (unsigned char*)(W2t + (size_t)H2 * H1);   // N_NODES x 128 fp8
  int*            row_ptr = (int*)(ha8 + (size_t)N_NODES * H2);      // N_NODES+1 int

  float* ha_out = (float*)d_out;
  float* hp     = ha_out + (size_t)N_NODES * H2;

  prep_kernel<<<2048, 256, 0, stream>>>(W1, W2, adj_rows, W1t, W2t, row_ptr);
  mlp_kernel<<<ROWS_PAD / 64, 256, 0, stream>>>(seq_a, W1t, W2t, b1, b2, ha_out, ha8);
  agg_csr_kernel<<<(ROWS_PAD * 64) / 256, 256, 0, stream>>>(row_ptr, adj_cols, adj_vals, ha8, hp);
}

// Round 16
// 380.375 us; speedup vs baseline: 1.0257x; 1.0257x over previous
//
#include <hip/hip_runtime.h>

#define N_NODES 100000
#define ROWS_PAD 100096
#define NIN 512
#define H1  512
#define H2  128
#define N_EDGES 3200000

typedef __attribute__((ext_vector_type(8))) short bf16x8;
typedef __attribute__((ext_vector_type(4))) float f32x4;
typedef __attribute__((ext_vector_type(2))) float f32x2;

__device__ __forceinline__ unsigned short f2b(float x) {
  union { float f; unsigned int u; } c; c.f = x;
  unsigned int u = c.u;
  unsigned int r = (u + 0x7FFFu + ((u >> 16) & 1u)) >> 16;
  return (unsigned short)r;
}

typedef const __attribute__((address_space(1))) unsigned int* gp1_t;
typedef __attribute__((address_space(3))) unsigned int* sp3_t;
__device__ __forceinline__ void gl_lds16(const void* g, void* s) {
  __builtin_amdgcn_global_load_lds((gp1_t)g, (sp3_t)s, 16, 0, 0);
}

// packed f32x2 -> bf16x2 (RNE), 1 VALU inst
__device__ __forceinline__ unsigned cvtpk(float lo, float hi) {
  unsigned r;
  asm("v_cvt_pk_bf16_f32 %0, %1, %2" : "=v"(r) : "v"(lo), "v"(hi));
  return r;
}

// ---- prep: W1/W2 transpose+bf16 pre-swizzled + CSR row_ptr (one dispatch) ----
__global__ void prep_kernel(const float* __restrict__ W1, const float* __restrict__ W2,
                            const int* __restrict__ rows,
                            unsigned short* __restrict__ W1t, unsigned short* __restrict__ W2t,
                            int* __restrict__ row_ptr) {
  int idx = blockIdx.x * blockDim.x + threadIdx.x;
  int stride = gridDim.x * blockDim.x;
  for (int i = idx; i < H1 * NIN; i += stride) {
    int n = i >> 9, k = i & 511;
    W1t[i] = f2b(W1[(size_t)(k ^ ((n & 7) << 3)) * H1 + n]);
  }
  for (int i = idx; i < H2 * H1; i += stride) {
    int n = i >> 9, k = i & 511;
    W2t[i] = f2b(W2[(size_t)(k ^ ((n & 7) << 3)) * H2 + n]);
  }
  for (int e = idx; e < N_EDGES; e += stride) {
    int r = rows[e];
    int rp = (e == 0) ? -1 : rows[e - 1];
    for (int q = rp + 1; q <= r; ++q) row_ptr[q] = e;
  }
  int lastrow = rows[N_EDGES - 1];
  for (int q = idx; q <= N_NODES; q += stride)
    if (q > lastrow) row_ptr[q] = N_EDGES;
}

// ---- GEMM1: h_pre = relu(seq_a @ W1 + b1); fused f32->bf16 staging with A-reg prefetch ----
__global__ __launch_bounds__(256, 6) void gemm1_kernel(
    const float* __restrict__ A, const unsigned short* __restrict__ W1t,
    const float* __restrict__ b1, unsigned short* __restrict__ h_pre)
{
  __shared__ __align__(16) unsigned short SM[12288];   // 24 KB: A bf16 [0..4095], B [4096..12287]
  const int tid = threadIdx.x;
  const int w = tid >> 6, lane = tid & 63;
  const int l15 = lane & 15, lg = lane >> 4;
  const int wr = w & 1, wc = w >> 1;
  // bijective XCD swizzle: 6256 = 8 x 782; 4 col-blocks of a row-panel -> same XCD
  const int hw = blockIdx.x;
  const int work = (hw & 7) * 782 + (hw >> 3);
  const int row0 = (work >> 2) << 6;
  const int n0 = (work & 3) << 7;

  // A staging geometry: 4 threads/row, 16 f32 (64B) per thread per kt
  int arow = row0 + (tid >> 2);
  if (arow > N_NODES - 1) arow = N_NODES - 1;           // OOB clamp (stores masked later)
  const float* asrc = A + ((size_t)arow << 9) + ((tid & 3) << 4);
  const int alr  = tid >> 2;
  const int aswz = (alr & 7) << 4;
  const int ad0  = ((tid & 3) << 5);
  char* alds = (char*)SM + alr * 128;

  f32x4 acc[2][4];
  #pragma unroll
  for (int m = 0; m < 2; ++m)
    #pragma unroll
    for (int n = 0; n < 4; ++n) acc[m][n] = (f32x4){0.f, 0.f, 0.f, 0.f};

  const int so = tid * 16;

  // preload A regs for kt=0 (oldest vmem ops)
  f32x4 a0 = *(const f32x4*)(asrc);
  f32x4 a1 = *(const f32x4*)(asrc + 4);
  f32x4 a2 = *(const f32x4*)(asrc + 8);
  f32x4 a3 = *(const f32x4*)(asrc + 12);

  #pragma unroll
  for (int kt = 0; kt < 8; ++kt) {
    // B: global -> LDS direct (4 ops; drained at the pre-MFMA wait)
    #pragma unroll
    for (int it = 0; it < 4; ++it) {
      int o = it * 4096 + so;
      int r = o >> 7, kb = o & 127;
      gl_lds16((const char*)W1t + (((size_t)(n0 + r)) << 10) + (kt << 7) + kb, (char*)SM + 8192 + o);
    }
    // convert cur A regs (compiler waits the 4 oldest = A(kt); B stays in flight)
    uint4 w0, w1;
    w0.x = cvtpk(a0[0], a0[1]); w0.y = cvtpk(a0[2], a0[3]);
    w0.z = cvtpk(a1[0], a1[1]); w0.w = cvtpk(a1[2], a1[3]);
    w1.x = cvtpk(a2[0], a2[1]); w1.y = cvtpk(a2[2], a2[3]);
    w1.z = cvtpk(a3[0], a3[1]); w1.w = cvtpk(a3[2], a3[3]);
    *(uint4*)(alds + ((ad0 +  0) ^ aswz)) = w0;
    *(uint4*)(alds + ((ad0 + 16) ^ aswz)) = w1;
    // prefetch A regs for kt+1 as the NEWEST vmem ops, left in flight across MFMA
    __builtin_amdgcn_sched_barrier(0);
    if (kt < 7) {
      const float* anp = asrc + ((kt + 1) << 6);
      a0 = *(const f32x4*)(anp);
      a1 = *(const f32x4*)(anp + 4);
      a2 = *(const f32x4*)(anp + 8);
      a3 = *(const f32x4*)(anp + 12);
      __builtin_amdgcn_sched_barrier(0);
      asm volatile("s_waitcnt vmcnt(4) lgkmcnt(0)" ::: "memory");  // drain B + ds_writes, keep A(kt+1)
    } else {
      __builtin_amdgcn_sched_barrier(0);
      asm volatile("s_waitcnt vmcnt(0) lgkmcnt(0)" ::: "memory");
    }
    __builtin_amdgcn_s_barrier();
    __builtin_amdgcn_sched_barrier(0);
    #pragma unroll
    for (int ks = 0; ks < 2; ++ks) {
      bf16x8 af[2], bfr[4];
      #pragma unroll
      for (int m = 0; m < 2; ++m) {
        int r = wr * 32 + m * 16 + l15;
        af[m] = *(const bf16x8*)((const char*)SM + (r << 7) + (((ks << 6) + (lg << 4)) ^ ((r & 7) << 4)));
      }
      #pragma unroll
      for (int n = 0; n < 4; ++n) {
        int r = wc * 64 + n * 16 + l15;
        bfr[n] = *(const bf16x8*)((const char*)SM + 8192 + (r << 7) + (((ks << 6) + (lg << 4)) ^ ((r & 7) << 4)));
      }
      #pragma unroll
      for (int m = 0; m < 2; ++m)
        #pragma unroll
        for (int n = 0; n < 4; ++n)
          acc[m][n] = __builtin_amdgcn_mfma_f32_16x16x32_bf16(af[m], bfr[n], acc[m][n], 0, 0, 0);
    }
    __builtin_amdgcn_sched_barrier(0);
    __builtin_amdgcn_s_barrier();   // all waves' ds_reads retired before next kt's writes
  }

  // ---- epilogue: bias+relu -> bf16 (pre-swizzled layout) in LDS, then 16B coalesced stores ----
  #pragma unroll
  for (int n = 0; n < 4; ++n) {
    int cl = wc * 64 + n * 16 + l15;
    float bias = b1[n0 + cl];
    #pragma unroll
    for (int m = 0; m < 2; ++m) {
      #pragma unroll
      for (int q = 0; q < 4; ++q) {
        int rl = wr * 32 + m * 16 + lg * 4 + q;
        float v = acc[m][n][q] + bias;
        v = v > 0.f ? v : 0.f;
        SM[rl * 128 + (cl ^ ((rl & 7) << 3))] = f2b(v);
      }
    }
  }
  __syncthreads();
  #pragma unroll
  for (int p = 0; p < 4; ++p) {
    int ch = tid + p * 256;
    int row = ch >> 4, six = ch & 15;
    uint4 d = *(const uint4*)((const char*)SM + (ch << 4));
    *(uint4*)((char*)h_pre + (((size_t)(row0 + row)) << 10) + (n0 << 1) + (six << 4)) = d;
  }
}

// ---- GEMM2: ha = h_pre @ W2 + b2 -> f32 d_out + fp8 e4m3 gather table; 64x128 tile ----
__global__ __launch_bounds__(256, 6) void gemm2_kernel(
    const unsigned short* __restrict__ Hp, const unsigned short* __restrict__ W2t,
    const float* __restrict__ b2, float* __restrict__ ha_out, unsigned char* __restrict__ ha8)
{
  __shared__ __align__(16) unsigned short SM[12288];
  const int tid = threadIdx.x;
  const int w = tid >> 6, lane = tid & 63;
  const int l15 = lane & 15, lg = lane >> 4;
  const int wr = w & 1, wc = w >> 1;
  const int row0 = blockIdx.x << 6;

  f32x4 acc[2][4];
  #pragma unroll
  for (int m = 0; m < 2; ++m)
    #pragma unroll
    for (int n = 0; n < 4; ++n) acc[m][n] = (f32x4){0.f, 0.f, 0.f, 0.f};

  const int so = tid * 16;
  for (int kt = 0; kt < 8; ++kt) {
    #pragma unroll
    for (int it = 0; it < 2; ++it) {
      int o = it * 4096 + so;
      int r = o >> 7, kb = o & 127;
      gl_lds16((const char*)Hp + (((size_t)(row0 + r)) << 10) + (kt << 7) + kb, (char*)SM + o);
    }
    #pragma unroll
    for (int it = 0; it < 4; ++it) {
      int o = it * 4096 + so;
      int r = o >> 7, kb = o & 127;
      gl_lds16((const char*)W2t + (((size_t)r) << 10) + (kt << 7) + kb, (char*)SM + 8192 + o);
    }
    __syncthreads();
    #pragma unroll
    for (int ks = 0; ks < 2; ++ks) {
      bf16x8 af[2], bfr[4];
      #pragma unroll
      for (int m = 0; m < 2; ++m) {
        int r = wr * 32 + m * 16 + l15;
        af[m] = *(const bf16x8*)((const char*)SM + (r << 7) + (((ks << 6) + (lg << 4)) ^ ((r & 7) << 4)));
      }
      #pragma unroll
      for (int n = 0; n < 4; ++n) {
        int r = wc * 64 + n * 16 + l15;
        bfr[n] = *(const bf16x8*)((const char*)SM + 8192 + (r << 7) + (((ks << 6) + (lg << 4)) ^ ((r & 7) << 4)));
      }
      #pragma unroll
      for (int m = 0; m < 2; ++m)
        #pragma unroll
        for (int n = 0; n < 4; ++n)
          acc[m][n] = __builtin_amdgcn_mfma_f32_16x16x32_bf16(af[m], bfr[n], acc[m][n], 0, 0, 0);
    }
    __syncthreads();
  }

  #pragma unroll
  for (int n = 0; n < 4; ++n) {
    int col = wc * 64 + n * 16 + l15;
    float bias = b2[col];
    #pragma unroll
    for (int m = 0; m < 2; ++m) {
      #pragma unroll
      for (int q = 0; q < 4; ++q) {
        int row = row0 + wr * 32 + m * 16 + lg * 4 + q;
        if (row < N_NODES) {
          float v = acc[m][n][q] + bias;
          ha_out[((size_t)row << 7) + col] = v;
          int p8 = __builtin_amdgcn_cvt_pk_fp8_f32(v, v, 0, false);
          ha8[((size_t)row << 7) + col] = (unsigned char)(p8 & 0xff);
        }
      }
    }
  }
}

// ---- aggregation: CSR, one wave per row, fp8 table (2 cache lines/edge), no atomics ----
__global__ __launch_bounds__(256) void agg_csr_kernel(
    const int* __restrict__ row_ptr, const int* __restrict__ cols, const float* __restrict__ vals,
    const unsigned char* __restrict__ gtab8, float* __restrict__ hp)
{
  const int row = __builtin_amdgcn_readfirstlane((blockIdx.x * blockDim.x + threadIdx.x) >> 6);
  if (row >= N_NODES) return;
  const int lane = threadIdx.x & 63;
  const int e0 = row_ptr[row];
  const int e1 = row_ptr[row + 1];

  float acc0 = 0.f, acc1 = 0.f;
  int e = e0;
  for (; e + 8 <= e1; e += 8) {
    int c[8]; float v[8]; unsigned short g[8];
    #pragma unroll
    for (int j = 0; j < 8; ++j) { c[j] = cols[e + j]; v[j] = vals[e + j]; }
    #pragma unroll
    for (int j = 0; j < 8; ++j)
      g[j] = *(const unsigned short*)(gtab8 + ((size_t)c[j] << 7) + (lane << 1));
    float t0 = acc0, t1 = 0.f, u0 = acc1, u1 = 0.f;
    #pragma unroll
    for (int j = 0; j < 8; j += 2) {
      f32x2 f0 = __builtin_amdgcn_cvt_pk_f32_fp8((int)g[j+0], false);
      f32x2 f1 = __builtin_amdgcn_cvt_pk_f32_fp8((int)g[j+1], false);
      t0 = fmaf(v[j+0], f0.x, t0);
      t1 = fmaf(v[j+1], f1.x, t1);
      u0 = fmaf(v[j+0], f0.y, u0);
      u1 = fmaf(v[j+1], f1.y, u1);
    }
    acc0 = t0 + t1; acc1 = u0 + u1;
  }
  for (; e < e1; ++e) {
    int c = cols[e];
    float v = vals[e];
    unsigned short g = *(const unsigned short*)(gtab8 + ((size_t)c << 7) + (lane << 1));
    f32x2 f = __builtin_amdgcn_cvt_pk_f32_fp8((int)g, false);
    acc0 = fmaf(v, f.x, acc0);
    acc1 = fmaf(v, f.y, acc1);
  }
  float2 st; st.x = acc0; st.y = acc1;
  *(float2*)&hp[((size_t)row << 7) + (lane << 1)] = st;
}

extern "C" void kernel_launch(void* const* d_in, const int* in_sizes, int n_in,
                              void* d_out, int out_size, void* d_ws, size_t ws_size,
                              hipStream_t stream) {
  const float* seq_a    = (const float*)d_in[0];
  const float* W1       = (const float*)d_in[1];
  const float* b1       = (const float*)d_in[2];
  const float* W2       = (const float*)d_in[3];
  const float* b2       = (const float*)d_in[4];
  const int*   adj_rows = (const int*)d_in[5];
  const int*   adj_cols = (const int*)d_in[6];
  const float* adj_vals = (const float*)d_in[7];

  unsigned short* h_pre = (unsigned short*)d_ws;            // ROWS_PAD x 512 bf16 (swizzled)
  unsigned short* W1t   = h_pre + (size_t)ROWS_PAD * H1;    // 512 x 512 bf16
  unsigned short* W2t   = W1t + (size_t)H1 * NIN;           // 128 x 512 bf16
  unsigned char*  ha8   = (unsigned char*)(W2t + (size_t)H2 * H1);   // N_NODES x 128 fp8
  int*            row_ptr = (int*)(ha8 + (size_t)N_NODES * H2);      // N_NODES+1 int

  float* ha_out = (float*)d_out;
  float* hp     = ha_out + (size_t)N_NODES * H2;

  prep_kernel<<<2048, 256, 0, stream>>>(W1, W2, adj_rows, W1t, W2t, row_ptr);
  gemm1_kernel<<<6256, 256, 0, stream>>>(seq_a, W1t, b1, h_pre);
  gemm2_kernel<<<1564, 256, 0, stream>>>(h_pre, W2t, b2, ha_out, ha8);
  agg_csr_kernel<<<(ROWS_PAD * 64) / 256, 256, 0, stream>>>(row_ptr, adj_cols, adj_vals, ha8, hp);
}

// Round 17
// 254.026 us; speedup vs baseline: 1.5359x; 1.4974x over previous
//
#include <hip/hip_runtime.h>

#define N_NODES 100000
#define ROWS_PAD 100096
#define NIN 512
#define H1  512
#define H2  128
#define N_EDGES 3200000

typedef __attribute__((ext_vector_type(8))) short bf16x8;
typedef __attribute__((ext_vector_type(4))) float f32x4;
typedef __attribute__((ext_vector_type(2))) float f32x2;

__device__ __forceinline__ unsigned short f2b(float x) {
  union { float f; unsigned int u; } c; c.f = x;
  unsigned int u = c.u;
  unsigned int r = (u + 0x7FFFu + ((u >> 16) & 1u)) >> 16;
  return (unsigned short)r;
}

typedef const __attribute__((address_space(1))) unsigned int* gp1_t;
typedef __attribute__((address_space(3))) unsigned int* sp3_t;
__device__ __forceinline__ void gl_lds16(const void* g, void* s) {
  __builtin_amdgcn_global_load_lds((gp1_t)g, (sp3_t)s, 16, 0, 0);
}

// packed f32x2 -> bf16x2 (RNE), 1 VALU inst
__device__ __forceinline__ unsigned cvtpk(float lo, float hi) {
  unsigned r;
  asm("v_cvt_pk_bf16_f32 %0, %1, %2" : "=v"(r) : "v"(lo), "v"(hi));
  return r;
}

// ---- prep: W1/W2 transpose+bf16 pre-swizzled + CSR row_ptr (one dispatch) ----
__global__ void prep_kernel(const float* __restrict__ W1, const float* __restrict__ W2,
                            const int* __restrict__ rows,
                            unsigned short* __restrict__ W1t, unsigned short* __restrict__ W2t,
                            int* __restrict__ row_ptr) {
  int idx = blockIdx.x * blockDim.x + threadIdx.x;
  int stride = gridDim.x * blockDim.x;
  for (int i = idx; i < H1 * NIN; i += stride) {
    int n = i >> 9, k = i & 511;
    W1t[i] = f2b(W1[(size_t)(k ^ ((n & 7) << 3)) * H1 + n]);
  }
  for (int i = idx; i < H2 * H1; i += stride) {
    int n = i >> 9, k = i & 511;
    W2t[i] = f2b(W2[(size_t)(k ^ ((n & 7) << 3)) * H2 + n]);
  }
  for (int e = idx; e < N_EDGES; e += stride) {
    int r = rows[e];
    int rp = (e == 0) ? -1 : rows[e - 1];
    for (int q = rp + 1; q <= r; ++q) row_ptr[q] = e;
  }
  int lastrow = rows[N_EDGES - 1];
  for (int q = idx; q <= N_NODES; q += stride)
    if (q > lastrow) row_ptr[q] = N_EDGES;
}

// ---- GEMM1: h_pre = relu(seq_a @ W1 + b1); fused f32->bf16 staging with A-reg prefetch ----
__global__ __launch_bounds__(256, 5) void gemm1_kernel(
    const float* __restrict__ A, const unsigned short* __restrict__ W1t,
    const float* __restrict__ b1, unsigned short* __restrict__ h_pre)
{
  __shared__ __align__(16) unsigned short SM[12288];   // 24 KB: A bf16 [0..4095], B [4096..12287]
  const int tid = threadIdx.x;
  const int w = tid >> 6, lane = tid & 63;
  const int l15 = lane & 15, lg = lane >> 4;
  const int wr = w & 1, wc = w >> 1;
  // bijective XCD swizzle: 6256 = 8 x 782; 4 col-blocks of a row-panel -> same XCD
  const int hw = blockIdx.x;
  const int work = (hw & 7) * 782 + (hw >> 3);
  const int row0 = (work >> 2) << 6;
  const int n0 = (work & 3) << 7;

  // A staging geometry: 4 threads/row, 16 f32 (64B) per thread per kt
  int arow = row0 + (tid >> 2);
  if (arow > N_NODES - 1) arow = N_NODES - 1;           // OOB clamp (stores masked later)
  const float* asrc = A + ((size_t)arow << 9) + ((tid & 3) << 4);
  const int alr  = tid >> 2;
  const int aswz = (alr & 7) << 4;
  const int ad0  = ((tid & 3) << 5);
  char* alds = (char*)SM + alr * 128;

  f32x4 acc[2][4];
  #pragma unroll
  for (int m = 0; m < 2; ++m)
    #pragma unroll
    for (int n = 0; n < 4; ++n) acc[m][n] = (f32x4){0.f, 0.f, 0.f, 0.f};

  const int so = tid * 16;

  // preload A regs for kt=0 (oldest vmem ops)
  f32x4 a0 = *(const f32x4*)(asrc);
  f32x4 a1 = *(const f32x4*)(asrc + 4);
  f32x4 a2 = *(const f32x4*)(asrc + 8);
  f32x4 a3 = *(const f32x4*)(asrc + 12);

  #pragma unroll
  for (int kt = 0; kt < 8; ++kt) {
    // B: global -> LDS direct (4 ops; drained at the pre-MFMA wait)
    #pragma unroll
    for (int it = 0; it < 4; ++it) {
      int o = it * 4096 + so;
      int r = o >> 7, kb = o & 127;
      gl_lds16((const char*)W1t + (((size_t)(n0 + r)) << 10) + (kt << 7) + kb, (char*)SM + 8192 + o);
    }
    // convert cur A regs (compiler waits the 4 oldest = A(kt); B stays in flight)
    uint4 w0, w1;
    w0.x = cvtpk(a0[0], a0[1]); w0.y = cvtpk(a0[2], a0[3]);
    w0.z = cvtpk(a1[0], a1[1]); w0.w = cvtpk(a1[2], a1[3]);
    w1.x = cvtpk(a2[0], a2[1]); w1.y = cvtpk(a2[2], a2[3]);
    w1.z = cvtpk(a3[0], a3[1]); w1.w = cvtpk(a3[2], a3[3]);
    *(uint4*)(alds + ((ad0 +  0) ^ aswz)) = w0;
    *(uint4*)(alds + ((ad0 + 16) ^ aswz)) = w1;
    // prefetch A regs for kt+1 as the NEWEST vmem ops, left in flight across MFMA
    __builtin_amdgcn_sched_barrier(0);
    if (kt < 7) {
      const float* anp = asrc + ((kt + 1) << 6);
      a0 = *(const f32x4*)(anp);
      a1 = *(const f32x4*)(anp + 4);
      a2 = *(const f32x4*)(anp + 8);
      a3 = *(const f32x4*)(anp + 12);
      __builtin_amdgcn_sched_barrier(0);
      asm volatile("s_waitcnt vmcnt(4) lgkmcnt(0)" ::: "memory");  // drain B + ds_writes, keep A(kt+1)
    } else {
      __builtin_amdgcn_sched_barrier(0);
      asm volatile("s_waitcnt vmcnt(0) lgkmcnt(0)" ::: "memory");
    }
    __builtin_amdgcn_s_barrier();
    __builtin_amdgcn_sched_barrier(0);
    #pragma unroll
    for (int ks = 0; ks < 2; ++ks) {
      bf16x8 af[2], bfr[4];
      #pragma unroll
      for (int m = 0; m < 2; ++m) {
        int r = wr * 32 + m * 16 + l15;
        af[m] = *(const bf16x8*)((const char*)SM + (r << 7) + (((ks << 6) + (lg << 4)) ^ ((r & 7) << 4)));
      }
      #pragma unroll
      for (int n = 0; n < 4; ++n) {
        int r = wc * 64 + n * 16 + l15;
        bfr[n] = *(const bf16x8*)((const char*)SM + 8192 + (r << 7) + (((ks << 6) + (lg << 4)) ^ ((r & 7) << 4)));
      }
      #pragma unroll
      for (int m = 0; m < 2; ++m)
        #pragma unroll
        for (int n = 0; n < 4; ++n)
          acc[m][n] = __builtin_amdgcn_mfma_f32_16x16x32_bf16(af[m], bfr[n], acc[m][n], 0, 0, 0);
    }
    __builtin_amdgcn_sched_barrier(0);
    __builtin_amdgcn_s_barrier();   // all waves' ds_reads retired before next kt's writes
  }

  // ---- epilogue: bias+relu -> bf16 (pre-swizzled layout) in LDS, then 16B coalesced stores ----
  #pragma unroll
  for (int n = 0; n < 4; ++n) {
    int cl = wc * 64 + n * 16 + l15;
    float bias = b1[n0 + cl];
    #pragma unroll
    for (int m = 0; m < 2; ++m) {
      #pragma unroll
      for (int q = 0; q < 4; ++q) {
        int rl = wr * 32 + m * 16 + lg * 4 + q;
        float v = acc[m][n][q] + bias;
        v = v > 0.f ? v : 0.f;
        SM[rl * 128 + (cl ^ ((rl & 7) << 3))] = f2b(v);
      }
    }
  }
  __syncthreads();
  #pragma unroll
  for (int p = 0; p < 4; ++p) {
    int ch = tid + p * 256;
    int row = ch >> 4, six = ch & 15;
    uint4 d = *(const uint4*)((const char*)SM + (ch << 4));
    *(uint4*)((char*)h_pre + (((size_t)(row0 + row)) << 10) + (n0 << 1) + (six << 4)) = d;
  }
}

// ---- GEMM2: ha = h_pre @ W2 + b2 -> f32 d_out + fp8 e4m3 gather table; 64x128 tile ----
__global__ __launch_bounds__(256, 5) void gemm2_kernel(
    const unsigned short* __restrict__ Hp, const unsigned short* __restrict__ W2t,
    const float* __restrict__ b2, float* __restrict__ ha_out, unsigned char* __restrict__ ha8)
{
  __shared__ __align__(16) unsigned short SM[12288];
  const int tid = threadIdx.x;
  const int w = tid >> 6, lane = tid & 63;
  const int l15 = lane & 15, lg = lane >> 4;
  const int wr = w & 1, wc = w >> 1;
  const int row0 = blockIdx.x << 6;

  f32x4 acc[2][4];
  #pragma unroll
  for (int m = 0; m < 2; ++m)
    #pragma unroll
    for (int n = 0; n < 4; ++n) acc[m][n] = (f32x4){0.f, 0.f, 0.f, 0.f};

  const int so = tid * 16;
  for (int kt = 0; kt < 8; ++kt) {
    #pragma unroll
    for (int it = 0; it < 2; ++it) {
      int o = it * 4096 + so;
      int r = o >> 7, kb = o & 127;
      gl_lds16((const char*)Hp + (((size_t)(row0 + r)) << 10) + (kt << 7) + kb, (char*)SM + o);
    }
    #pragma unroll
    for (int it = 0; it < 4; ++it) {
      int o = it * 4096 + so;
      int r = o >> 7, kb = o & 127;
      gl_lds16((const char*)W2t + (((size_t)r) << 10) + (kt << 7) + kb, (char*)SM + 8192 + o);
    }
    __syncthreads();
    #pragma unroll
    for (int ks = 0; ks < 2; ++ks) {
      bf16x8 af[2], bfr[4];
      #pragma unroll
      for (int m = 0; m < 2; ++m) {
        int r = wr * 32 + m * 16 + l15;
        af[m] = *(const bf16x8*)((const char*)SM + (r << 7) + (((ks << 6) + (lg << 4)) ^ ((r & 7) << 4)));
      }
      #pragma unroll
      for (int n = 0; n < 4; ++n) {
        int r = wc * 64 + n * 16 + l15;
        bfr[n] = *(const bf16x8*)((const char*)SM + 8192 + (r << 7) + (((ks << 6) + (lg << 4)) ^ ((r & 7) << 4)));
      }
      #pragma unroll
      for (int m = 0; m < 2; ++m)
        #pragma unroll
        for (int n = 0; n < 4; ++n)
          acc[m][n] = __builtin_amdgcn_mfma_f32_16x16x32_bf16(af[m], bfr[n], acc[m][n], 0, 0, 0);
    }
    __syncthreads();
  }

  #pragma unroll
  for (int n = 0; n < 4; ++n) {
    int col = wc * 64 + n * 16 + l15;
    float bias = b2[col];
    #pragma unroll
    for (int m = 0; m < 2; ++m) {
      #pragma unroll
      for (int q = 0; q < 4; ++q) {
        int row = row0 + wr * 32 + m * 16 + lg * 4 + q;
        if (row < N_NODES) {
          float v = acc[m][n][q] + bias;
          ha_out[((size_t)row << 7) + col] = v;
          int p8 = __builtin_amdgcn_cvt_pk_fp8_f32(v, v, 0, false);
          ha8[((size_t)row << 7) + col] = (unsigned char)(p8 & 0xff);
        }
      }
    }
  }
}

// ---- aggregation: CSR, one wave per row, fp8 table (2 cache lines/edge), no atomics ----
__global__ __launch_bounds__(256) void agg_csr_kernel(
    const int* __restrict__ row_ptr, const int* __restrict__ cols, const float* __restrict__ vals,
    const unsigned char* __restrict__ gtab8, float* __restrict__ hp)
{
  const int row = __builtin_amdgcn_readfirstlane((blockIdx.x * blockDim.x + threadIdx.x) >> 6);
  if (row >= N_NODES) return;
  const int lane = threadIdx.x & 63;
  const int e0 = row_ptr[row];
  const int e1 = row_ptr[row + 1];

  float acc0 = 0.f, acc1 = 0.f;
  int e = e0;
  for (; e + 8 <= e1; e += 8) {
    int c[8]; float v[8]; unsigned short g[8];
    #pragma unroll
    for (int j = 0; j < 8; ++j) { c[j] = cols[e + j]; v[j] = vals[e + j]; }
    #pragma unroll
    for (int j = 0; j < 8; ++j)
      g[j] = *(const unsigned short*)(gtab8 + ((size_t)c[j] << 7) + (lane << 1));
    float t0 = acc0, t1 = 0.f, u0 = acc1, u1 = 0.f;
    #pragma unroll
    for (int j = 0; j < 8; j += 2) {
      f32x2 f0 = __builtin_amdgcn_cvt_pk_f32_fp8((int)g[j+0], false);
      f32x2 f1 = __builtin_amdgcn_cvt_pk_f32_fp8((int)g[j+1], false);
      t0 = fmaf(v[j+0], f0.x, t0);
      t1 = fmaf(v[j+1], f1.x, t1);
      u0 = fmaf(v[j+0], f0.y, u0);
      u1 = fmaf(v[j+1], f1.y, u1);
    }
    acc0 = t0 + t1; acc1 = u0 + u1;
  }
  for (; e < e1; ++e) {
    int c = cols[e];
    float v = vals[e];
    unsigned short g = *(const unsigned short*)(gtab8 + ((size_t)c << 7) + (lane << 1));
    f32x2 f = __builtin_amdgcn_cvt_pk_f32_fp8((int)g, false);
    acc0 = fmaf(v, f.x, acc0);
    acc1 = fmaf(v, f.y, acc1);
  }
  float2 st; st.x = acc0; st.y = acc1;
  *(float2*)&hp[((size_t)row << 7) + (lane << 1)] = st;
}

extern "C" void kernel_launch(void* const* d_in, const int* in_sizes, int n_in,
                              void* d_out, int out_size, void* d_ws, size_t ws_size,
                              hipStream_t stream) {
  const float* seq_a    = (const float*)d_in[0];
  const float* W1       = (const float*)d_in[1];
  const float* b1       = (const float*)d_in[2];
  const float* W2       = (const float*)d_in[3];
  const float* b2       = (const float*)d_in[4];
  const int*   adj_rows = (const int*)d_in[5];
  const int*   adj_cols = (const int*)d_in[6];
  const float* adj_vals = (const float*)d_in[7];

  unsigned short* h_pre = (unsigned short*)d_ws;            // ROWS_PAD x 512 bf16 (swizzled)
  unsigned short* W1t   = h_pre + (size_t)ROWS_PAD * H1;    // 512 x 512 bf16
  unsigned short* W2t   = W1t + (size_t)H1 * NIN;           // 128 x 512 bf16
  unsigned char*  ha8   = (unsigned char*)(W2t + (size_t)H2 * H1);   // N_NODES x 128 fp8
  int*            row_ptr = (int*)(ha8 + (size_t)N_NODES * H2);      // N_NODES+1 int

  float* ha_out = (float*)d_out;
  float* hp     = ha_out + (size_t)N_NODES * H2;

  prep_kernel<<<2048, 256, 0, stream>>>(W1, W2, adj_rows, W1t, W2t, row_ptr);
  gemm1_kernel<<<6256, 256, 0, stream>>>(seq_a, W1t, b1, h_pre);
  gemm2_kernel<<<1564, 256, 0, stream>>>(h_pre, W2t, b2, ha_out, ha8);
  agg_csr_kernel<<<(ROWS_PAD * 64) / 256, 256, 0, stream>>>(row_ptr, adj_cols, adj_vals, ha8, hp);
}